// Round 2
// baseline (1355.482 us; speedup 1.0000x reference)
//
#include <hip/hip_runtime.h>

#define BB 64
#define TT 1024
#define CC 256

#define REP16(X) X(0) X(1) X(2) X(3) X(4) X(5) X(6) X(7) \
                 X(8) X(9) X(10) X(11) X(12) X(13) X(14) X(15)

// One workgroup per batch chain (sequential in t). 1024 threads = 16 waves.
// Thread (grp = tid>>8, j = tid&255) holds W[grp*64+k][j] = exp(trans[b, grp*64+k, j])
// in 64 named VGPRs (16 float4 SSA values — NOT an array; round-1's float W[64]
// was demoted to scratch: VGPR_Count=52, 4x slowdown).
__global__ __launch_bounds__(1024, 4)
void crf_fwd(const float* __restrict__ emis,      // [B,T,C]
             const float* __restrict__ trans,     // [B,C,C]
             const int* __restrict__ seq_lens,    // [B]
             float* __restrict__ out_alpha,       // [B,T,C]
             float* __restrict__ out_logz)        // [B]
{
  const int b = blockIdx.x;
  const int tid = threadIdx.x;
  const int j = tid & (CC - 1);
  const int grp = tid >> 8;      // 0..3 : which 64-row slab of W
  const int lane = tid & 63;
  const int g64 = grp * 64;

  __shared__ float s_alpha[CC];
  __shared__ float s_p[CC];
  __shared__ float s_part[4][CC];
  __shared__ float s_last[CC];
  __shared__ float s_wmax[4];

  // ---- One-time: W slab into named registers (coalesced across j per k) ----
  const float* tb = trans + (size_t)b * CC * CC + (size_t)g64 * CC + j;
#define DECLW(q) float4 W##q;
  REP16(DECLW)
#define INITW(q) \
  W##q.x = __expf(tb[(4*q+0)*CC]); \
  W##q.y = __expf(tb[(4*q+1)*CC]); \
  W##q.z = __expf(tb[(4*q+2)*CC]); \
  W##q.w = __expf(tb[(4*q+3)*CC]);
  REP16(INITW)

  const float* eb = emis + (size_t)b * TT * CC;
  float* ab = out_alpha + (size_t)b * TT * CC;
  const int L = seq_lens[b];

  // ---- t = 0 ----
  if (tid < CC) {
    float a0 = eb[j];
    s_alpha[j] = a0;
    ab[j] = a0;
    if (L == 1) s_last[j] = a0;
    float wm = a0;
    #pragma unroll
    for (int off = 32; off >= 1; off >>= 1)
      wm = fmaxf(wm, __shfl_xor(wm, off, 64));
    if (lane == 0) s_wmax[tid >> 6] = wm;
  }
  __syncthreads();

  // ---- main chain ----
  for (int t = 1; t < TT; ++t) {
    float e_t = 0.f, m = 0.f;
    if (tid < CC) {
      e_t = eb[(size_t)t * CC + j];   // prefetched; consumed after barrier B
      m = fmaxf(fmaxf(s_wmax[0], s_wmax[1]), fmaxf(s_wmax[2], s_wmax[3]));
      s_p[j] = __expf(s_alpha[j] - m);
    }
    __syncthreads();  // A: p ready

    // matvec partial: acc = sum_k p[g64+k] * W[k][j], W in named regs
    float a0 = 0.f, a1 = 0.f, a2 = 0.f, a3 = 0.f;
    const float4* p4 = (const float4*)(s_p + g64);
#define FMAW(q) { float4 pv = p4[q]; \
    a0 = fmaf(pv.x, W##q.x, a0); \
    a1 = fmaf(pv.y, W##q.y, a1); \
    a2 = fmaf(pv.z, W##q.z, a2); \
    a3 = fmaf(pv.w, W##q.w, a3); }
    REP16(FMAW)
    s_part[grp][j] = (a0 + a1) + (a2 + a3);
    __syncthreads();  // B: partials ready

    if (tid < CC) {
      float s = (s_part[0][j] + s_part[1][j]) + (s_part[2][j] + s_part[3][j]);
      float anew = e_t + m + __logf(s);
      s_alpha[j] = anew;
      ab[(size_t)t * CC + j] = anew;
      if (t == L - 1) s_last[j] = anew;
      float wm = anew;                 // fold next step's max into this phase
      #pragma unroll
      for (int off = 32; off >= 1; off >>= 1)
        wm = fmaxf(wm, __shfl_xor(wm, off, 64));
      if (lane == 0) s_wmax[tid >> 6] = wm;
    }
    __syncthreads();  // C: alpha/wmax ready for next step
  }

  // ---- log_Z = logsumexp_j(s_last) by wave 0 ----
  if (tid < 64) {
    float4 v = ((const float4*)s_last)[lane];
    float m = fmaxf(fmaxf(v.x, v.y), fmaxf(v.z, v.w));
    #pragma unroll
    for (int off = 32; off >= 1; off >>= 1)
      m = fmaxf(m, __shfl_xor(m, off, 64));
    float s = __expf(v.x - m) + __expf(v.y - m) + __expf(v.z - m) + __expf(v.w - m);
    #pragma unroll
    for (int off = 32; off >= 1; off >>= 1)
      s += __shfl_xor(s, off, 64);
    if (lane == 0) out_logz[b] = m + __logf(s);
  }
}

extern "C" void kernel_launch(void* const* d_in, const int* in_sizes, int n_in,
                              void* d_out, int out_size, void* d_ws, size_t ws_size,
                              hipStream_t stream) {
  const float* emis = (const float*)d_in[0];
  const float* trans = (const float*)d_in[1];
  const int* seq_lens = (const int*)d_in[2];
  float* out_alpha = (float*)d_out;
  float* out_logz = out_alpha + (size_t)BB * TT * CC;
  hipLaunchKernelGGL(crf_fwd, dim3(BB), dim3(1024), 0, stream,
                     emis, trans, seq_lens, out_alpha, out_logz);
}

// Round 3
// 1004.498 us; speedup vs baseline: 1.3494x; 1.3494x over previous
//
#include <hip/hip_runtime.h>

#define BB 64
#define TT 1024
#define CC 256

typedef short v8s __attribute__((ext_vector_type(8)));
typedef float v4f __attribute__((ext_vector_type(4)));

#define REP8(X) X(0) X(1) X(2) X(3) X(4) X(5) X(6) X(7)

// fp32 -> bf16 round-to-nearest-even (finite inputs)
static __device__ __forceinline__ short f2bf(float f) {
  unsigned u = __float_as_uint(f);
  return (short)((u + 0x7FFFu + ((u >> 16) & 1u)) >> 16);
}

// One block (512 thr = 8 waves) per batch chain, sequential over t.
// Per step: alpha -> p = exp(alpha-m) in bf16 (threads<256) -> MFMA matvec
// r[n] = sum_k p[k]*W[k][n] with W register-resident as B-fragments ->
// alpha' = e_t + m + log(r). A-operand = p broadcast to all 16 M rows
// (every lane in a quad reads the same 8 bf16), so all D rows are the
// identical correct result; lanes with quad==0 write row 0.
// Fragment layouts (verified, guide §3): A[m=lane&15][k=quad*8+e],
// B[k=quad*8+e][n=lane&15], C/D col=lane&15.
__global__ __launch_bounds__(512, 2)
void crf_fwd(const float* __restrict__ emis,      // [B,T,C]
             const float* __restrict__ trans,     // [B,C,C]
             const int* __restrict__ seq_lens,    // [B]
             float* __restrict__ out_alpha,       // [B,T,C]
             float* __restrict__ out_logz)        // [B]
{
  const int b = blockIdx.x;
  const int tid = threadIdx.x;
  const int lane = tid & 63;
  const int wv = tid >> 6;        // wave 0..7 -> cols [32*wv, 32*wv+32)
  const int quad = lane >> 4;     // 0..3
  const int nl = lane & 15;
  const int k0q = quad * 8;

  __shared__ unsigned short __align__(16) s_pbf[CC];  // p in bf16
  __shared__ float s_r[CC];                           // matvec result
  __shared__ float __align__(16) s_last[CC];          // alpha at L-1
  __shared__ float s_wmax[4];                         // per-wave maxes

  // ---- one-time: W = exp(trans) into 16 named B-fragments per wave ----
  const float* tb = trans + (size_t)b * CC * CC;
  const int n0 = wv * 32 + nl;    // column for ct0; ct1 = n0 + 16
#define DECLB(q) v8s B0_##q, B1_##q;
  REP8(DECLB)
#define INITB(q) { \
  const float* pp = tb + (size_t)(q * 32 + k0q) * CC + n0; \
  B0_##q = (v8s){ f2bf(__expf(pp[0*CC])), f2bf(__expf(pp[1*CC])), \
                  f2bf(__expf(pp[2*CC])), f2bf(__expf(pp[3*CC])), \
                  f2bf(__expf(pp[4*CC])), f2bf(__expf(pp[5*CC])), \
                  f2bf(__expf(pp[6*CC])), f2bf(__expf(pp[7*CC])) }; \
  const float* qq = pp + 16; \
  B1_##q = (v8s){ f2bf(__expf(qq[0*CC])), f2bf(__expf(qq[1*CC])), \
                  f2bf(__expf(qq[2*CC])), f2bf(__expf(qq[3*CC])), \
                  f2bf(__expf(qq[4*CC])), f2bf(__expf(qq[5*CC])), \
                  f2bf(__expf(qq[6*CC])), f2bf(__expf(qq[7*CC])) }; }
  REP8(INITB)

  const float* eb = emis + (size_t)b * TT * CC;
  float* ab = out_alpha + (size_t)b * TT * CC;
  const int L = seq_lens[b];

  // ---- t = 0 (threads < 256 own state j = tid) ----
  float alpha = 0.f;
  if (tid < CC) {
    alpha = eb[tid];
    ab[tid] = alpha;
    if (L == 1) s_last[tid] = alpha;
    float wm = alpha;
    #pragma unroll
    for (int off = 32; off >= 1; off >>= 1)
      wm = fmaxf(wm, __shfl_xor(wm, off, 64));
    if (lane == 0) s_wmax[wv] = wm;
  }
  __syncthreads();

  // ---- main chain ----
  for (int t = 1; t < TT; ++t) {
    float e_t = 0.f, m = 0.f;
    if (tid < CC) {
      e_t = eb[(size_t)t * CC + tid];          // prefetch; used after barrier B
      m = fmaxf(fmaxf(s_wmax[0], s_wmax[1]), fmaxf(s_wmax[2], s_wmax[3]));
      s_pbf[tid] = (unsigned short)f2bf(__expf(alpha - m));
    }
    __syncthreads();  // A: p ready

    v4f acc0 = {0.f, 0.f, 0.f, 0.f}, acc1 = {0.f, 0.f, 0.f, 0.f};
#define MF(q) { v8s a_ = *(const v8s*)(const void*)(s_pbf + q * 32 + k0q); \
    acc0 = __builtin_amdgcn_mfma_f32_16x16x32_bf16(a_, B0_##q, acc0, 0, 0, 0); \
    acc1 = __builtin_amdgcn_mfma_f32_16x16x32_bf16(a_, B1_##q, acc1, 0, 0, 0); }
    REP8(MF)
    if (quad == 0) {                 // row 0 of D; all rows identical
      s_r[wv * 32 + nl]      = acc0[0];
      s_r[wv * 32 + 16 + nl] = acc1[0];
    }
    __syncthreads();  // B: r ready

    if (tid < CC) {
      float anew = e_t + m + __logf(s_r[tid]);
      alpha = anew;
      ab[(size_t)t * CC + tid] = anew;
      if (t == L - 1) s_last[tid] = anew;
      float wm = anew;               // fold next step's max into this phase
      #pragma unroll
      for (int off = 32; off >= 1; off >>= 1)
        wm = fmaxf(wm, __shfl_xor(wm, off, 64));
      if (lane == 0) s_wmax[wv] = wm;
    }
    __syncthreads();  // C: alpha/wmax ready
  }

  // ---- log_Z = logsumexp_j(s_last), wave 0 ----
  if (tid < 64) {
    float4 v = ((const float4*)s_last)[lane];
    float m = fmaxf(fmaxf(v.x, v.y), fmaxf(v.z, v.w));
    #pragma unroll
    for (int off = 32; off >= 1; off >>= 1)
      m = fmaxf(m, __shfl_xor(m, off, 64));
    float s = __expf(v.x - m) + __expf(v.y - m) + __expf(v.z - m) + __expf(v.w - m);
    #pragma unroll
    for (int off = 32; off >= 1; off >>= 1)
      s += __shfl_xor(s, off, 64);
    if (lane == 0) out_logz[b] = m + __logf(s);
  }
}

extern "C" void kernel_launch(void* const* d_in, const int* in_sizes, int n_in,
                              void* d_out, int out_size, void* d_ws, size_t ws_size,
                              hipStream_t stream) {
  const float* emis = (const float*)d_in[0];
  const float* trans = (const float*)d_in[1];
  const int* seq_lens = (const int*)d_in[2];
  float* out_alpha = (float*)d_out;
  float* out_logz = out_alpha + (size_t)BB * TT * CC;
  hipLaunchKernelGGL(crf_fwd, dim3(BB), dim3(512), 0, stream,
                     emis, trans, seq_lens, out_alpha, out_logz);
}

// Round 4
// 720.618 us; speedup vs baseline: 1.8810x; 1.3939x over previous
//
#include <hip/hip_runtime.h>

#define BB 64
#define TT 1024
#define CC 256

typedef short v8s __attribute__((ext_vector_type(8)));
typedef float v4f __attribute__((ext_vector_type(4)));

#define REP8(X) X(0) X(1) X(2) X(3) X(4) X(5) X(6) X(7)

// fp32 -> bf16 round-to-nearest-even (finite inputs)
static __device__ __forceinline__ short f2bf(float f) {
  unsigned u = __float_as_uint(f);
  return (short)((u + 0x7FFFu + ((u >> 16) & 1u)) >> 16);
}

// One block (512 thr = 8 waves) per batch chain, sequential over t.
// 2 barriers/step. Normalizer = alpha[t,0] (NOT max): p_j = exp(anew_j-anew_0)
// computed from LDS-broadcast r[0], e[0] — no shuffle-reduce, no s_wmax.
// Spread bound: |anew_j - anew_0| <= ~28 -> p <= e^28, fp32 sum <= ~9e16. Safe.
// Waves 4-7 stage e[t+1] (global, issued at M-phase top, drained at barrier B)
// into double-buffered s_e; scalar phase reads LDS only. Emission slab is
// pre-warmed into L3 (1 MB/block) so in-loop loads are ~L3 hits, not HBM.
// W = exp(trans) register-resident as 16 named bf16 B-fragments per wave.
__global__ __launch_bounds__(512, 2)
void crf_fwd(const float* __restrict__ emis,      // [B,T,C]
             const float* __restrict__ trans,     // [B,C,C]
             const int* __restrict__ seq_lens,    // [B]
             float* __restrict__ out_alpha,       // [B,T,C]
             float* __restrict__ out_logz)        // [B]
{
  const int b = blockIdx.x;
  const int tid = threadIdx.x;
  const int lane = tid & 63;
  const int wv = tid >> 6;        // wave 0..7 -> cols [32*wv, 32*wv+32)
  const int quad = lane >> 4;     // 0..3
  const int nl = lane & 15;
  const int k0q = quad * 8;

  __shared__ unsigned short __align__(16) s_pbf[CC];  // p in bf16
  __shared__ float s_r[CC];                           // matvec result
  __shared__ float s_e[2][CC];                        // staged emissions
  __shared__ float __align__(16) s_last[CC];          // alpha at L-1

  const float* eb = emis + (size_t)b * TT * CC;
  float* ab = out_alpha + (size_t)b * TT * CC;
  const int L = seq_lens[b];

  // ---- L3 pre-warm: stream this block's 1 MB emission slab once ----
  {
    const float4* e4 = (const float4*)eb;
    float acc = 0.f;
    #pragma unroll 4
    for (int i = tid; i < TT * CC / 4; i += 512) {
      float4 v = e4[i];
      acc += (v.x + v.y) + (v.z + v.w);
    }
    if (acc == 1.25e38f) s_r[0] = acc;   // never true; defeats DCE
  }

  // ---- one-time: W = exp(trans) into 16 named B-fragments per wave ----
  const float* tb = trans + (size_t)b * CC * CC;
  const int n0 = wv * 32 + nl;    // column for tile0; tile1 = n0 + 16
#define DECLB(q) v8s B0_##q, B1_##q;
  REP8(DECLB)
#define INITB(q) { \
  const float* pp = tb + (size_t)(q * 32 + k0q) * CC + n0; \
  B0_##q = (v8s){ f2bf(__expf(pp[0*CC])), f2bf(__expf(pp[1*CC])), \
                  f2bf(__expf(pp[2*CC])), f2bf(__expf(pp[3*CC])), \
                  f2bf(__expf(pp[4*CC])), f2bf(__expf(pp[5*CC])), \
                  f2bf(__expf(pp[6*CC])), f2bf(__expf(pp[7*CC])) }; \
  const float* qq = pp + 16; \
  B1_##q = (v8s){ f2bf(__expf(qq[0*CC])), f2bf(__expf(qq[1*CC])), \
                  f2bf(__expf(qq[2*CC])), f2bf(__expf(qq[3*CC])), \
                  f2bf(__expf(qq[4*CC])), f2bf(__expf(qq[5*CC])), \
                  f2bf(__expf(qq[6*CC])), f2bf(__expf(qq[7*CC])) }; }
  REP8(INITB)

  // ---- prologue: t = 0 ----
  float m_base = 0.f;   // alpha[t,0], tracked in-register by scalar threads
  float e_next = 0.f;   // waves 4-7: staged e[t+1]
  if (tid < CC) {
    float e0 = eb[tid];
    float e00 = eb[0];             // broadcast (same cache line region)
    ab[tid] = e0;
    if (L == 1) s_last[tid] = e0;
    m_base = e00;
    s_pbf[tid] = (unsigned short)f2bf(__expf(e0 - e00));
  } else {
    e_next = eb[CC + (tid - CC)];  // e[1]
    s_e[1][tid - CC] = e_next;
  }
  __syncthreads();

  // ---- main chain: 2 barriers/step ----
  for (int t = 1; t < TT; ++t) {
    // M phase (all 8 waves). Waves 4-7 first issue next emission load.
    if (tid >= CC) {
      int tn = (t + 1 < TT) ? t + 1 : t;     // harmless reload on last iter
      e_next = eb[(size_t)tn * CC + (tid - CC)];
    }
    // 16 MFMAs as 4 independent chains of 4 (latency), 2 col-tiles.
    v4f c0a = {0,0,0,0}, c0b = {0,0,0,0}, c1a = {0,0,0,0}, c1b = {0,0,0,0};
#define MFA(q) { v8s a_ = *(const v8s*)(const void*)(s_pbf + q * 32 + k0q); \
    c0a = __builtin_amdgcn_mfma_f32_16x16x32_bf16(a_, B0_##q, c0a, 0, 0, 0); \
    c1a = __builtin_amdgcn_mfma_f32_16x16x32_bf16(a_, B1_##q, c1a, 0, 0, 0); }
#define MFB(q) { v8s a_ = *(const v8s*)(const void*)(s_pbf + q * 32 + k0q); \
    c0b = __builtin_amdgcn_mfma_f32_16x16x32_bf16(a_, B0_##q, c0b, 0, 0, 0); \
    c1b = __builtin_amdgcn_mfma_f32_16x16x32_bf16(a_, B1_##q, c1b, 0, 0, 0); }
    MFA(0) MFB(4) MFA(1) MFB(5) MFA(2) MFB(6) MFA(3) MFB(7)
    if (quad == 0) {                // row 0 of D; all 16 rows identical
      s_r[wv * 32 + nl]      = c0a[0] + c0b[0];
      s_r[wv * 32 + 16 + nl] = c1a[0] + c1b[0];
    }
    __syncthreads();  // B: r ready

    // S phase: scalar update by waves 0-3; waves 4-7 publish e[t+1].
    if (tid < CC) {
      float rj  = s_r[tid];
      float r0  = s_r[0];            // broadcast
      float ej  = s_e[t & 1][tid];
      float ej0 = s_e[t & 1][0];     // broadcast
      float lr  = __logf(rj);
      float lr0 = __logf(r0);
      float anew = ej + m_base + lr;
      ab[(size_t)t * CC + tid] = anew;        // fire-and-forget store
      if (t == L - 1) s_last[tid] = anew;
      // p_j = exp(anew_j - anew_0); anew_0 = ej0 + m_base + lr0
      s_pbf[tid] = (unsigned short)f2bf(__expf((ej - ej0) + (lr - lr0)));
      m_base = ej0 + m_base + lr0;            // = anew_0
    } else {
      s_e[(t + 1) & 1][tid - CC] = e_next;
    }
    __syncthreads();  // C: p, e[t+1] ready
  }

  // ---- log_Z = logsumexp_j(s_last), wave 0 ----
  if (tid < 64) {
    float4 v = ((const float4*)s_last)[lane];
    float m = fmaxf(fmaxf(v.x, v.y), fmaxf(v.z, v.w));
    #pragma unroll
    for (int off = 32; off >= 1; off >>= 1)
      m = fmaxf(m, __shfl_xor(m, off, 64));
    float s = __expf(v.x - m) + __expf(v.y - m) + __expf(v.z - m) + __expf(v.w - m);
    #pragma unroll
    for (int off = 32; off >= 1; off >>= 1)
      s += __shfl_xor(s, off, 64);
    if (lane == 0) out_logz[b] = m + __logf(s);
  }
}

extern "C" void kernel_launch(void* const* d_in, const int* in_sizes, int n_in,
                              void* d_out, int out_size, void* d_ws, size_t ws_size,
                              hipStream_t stream) {
  const float* emis = (const float*)d_in[0];
  const float* trans = (const float*)d_in[1];
  const int* seq_lens = (const int*)d_in[2];
  float* out_alpha = (float*)d_out;
  float* out_logz = out_alpha + (size_t)BB * TT * CC;
  hipLaunchKernelGGL(crf_fwd, dim3(BB), dim3(512), 0, stream,
                     emis, trans, seq_lens, out_alpha, out_logz);
}